// Round 1
// baseline (42.914 us; speedup 1.0000x reference)
//
#include <hip/hip_runtime.h>

// out[b,u] = tanh( exp( max_i x[b,i]*W[i,u] ) - 1 + bias[u] )
// (exp is monotonic -> max commutes with exp; reduces to max-times GEMM)

#define BATCH 2048
#define INDIM 512
#define UNITS 512

#define BM 64
#define BN 64
#define BK 32
#define XS 66   // xsT row stride (floats): even (b64-aligned reads), breaks bank aliasing
#define WS 64   // ws row stride (floats): b128-aligned, 2-way conflicts only (free)

__global__ __launch_bounds__(512) void maxexp_kernel(
    const float* __restrict__ x,     // [BATCH][INDIM]
    const float* __restrict__ W,     // [INDIM][UNITS]
    const float* __restrict__ bias,  // [UNITS]
    float* __restrict__ out)         // [BATCH][UNITS]
{
    __shared__ float xsT[BK * XS];   // transposed x tile: [k][row]
    __shared__ float ws [BK * WS];   // W tile: [k][col]

    const int tid = threadIdx.x;
    const int tx  = tid & 15;        // 0..15  -> unit columns (4 each)
    const int ty  = tid >> 4;        // 0..31  -> batch rows   (2 each)
    const int u0  = blockIdx.x * BN;
    const int b0  = blockIdx.y * BM;

    // staging thread->element maps (coalesced float4 global loads)
    const int xr = tid >> 3;         // 0..63 : x tile row
    const int xc = (tid & 7) * 4;    // 0..28 : x tile col (k)
    const int wr = tid >> 4;         // 0..31 : W tile row (k)
    const int wc = (tid & 15) * 4;   // 0..60 : W tile col (u)

    float acc[2][4];
#pragma unroll
    for (int i = 0; i < 2; ++i)
#pragma unroll
        for (int j = 0; j < 4; ++j) acc[i][j] = -3.4e38f;

    const float* xg = x + (size_t)(b0 + xr) * INDIM + xc;
    const float* wg = W + (size_t)wr * UNITS + u0 + wc;

    for (int kt = 0; kt < INDIM / BK; ++kt) {
        const float4 xv = *reinterpret_cast<const float4*>(xg + kt * BK);
        const float4 wv = *reinterpret_cast<const float4*>(wg + (size_t)kt * BK * UNITS);

        // transpose-store x tile (scalar writes; 2-way conflicts max -> free)
        xsT[(xc + 0) * XS + xr] = xv.x;
        xsT[(xc + 1) * XS + xr] = xv.y;
        xsT[(xc + 2) * XS + xr] = xv.z;
        xsT[(xc + 3) * XS + xr] = xv.w;
        // direct store W tile
        *reinterpret_cast<float4*>(&ws[wr * WS + wc]) = wv;

        __syncthreads();

#pragma unroll
        for (int kk = 0; kk < BK; ++kk) {
            const float2 xv2 = *reinterpret_cast<const float2*>(&xsT[kk * XS + 2 * ty]);
            const float4 wv4 = *reinterpret_cast<const float4*>(&ws [kk * WS + 4 * tx]);
            acc[0][0] = fmaxf(acc[0][0], xv2.x * wv4.x);
            acc[0][1] = fmaxf(acc[0][1], xv2.x * wv4.y);
            acc[0][2] = fmaxf(acc[0][2], xv2.x * wv4.z);
            acc[0][3] = fmaxf(acc[0][3], xv2.x * wv4.w);
            acc[1][0] = fmaxf(acc[1][0], xv2.y * wv4.x);
            acc[1][1] = fmaxf(acc[1][1], xv2.y * wv4.y);
            acc[1][2] = fmaxf(acc[1][2], xv2.y * wv4.z);
            acc[1][3] = fmaxf(acc[1][3], xv2.y * wv4.w);
        }

        __syncthreads();
    }

    // epilogue: tanh(exp(m) - 1 + bias)
    const float4 bv = *reinterpret_cast<const float4*>(bias + u0 + 4 * tx);
    const float bb[4] = {bv.x, bv.y, bv.z, bv.w};

#pragma unroll
    for (int i = 0; i < 2; ++i) {
        float4 o;
        float r[4];
#pragma unroll
        for (int j = 0; j < 4; ++j) {
            const float p = __expf(acc[i][j]) - 1.0f + bb[j];
            const float e = __expf(2.0f * p);
            r[j] = 1.0f - 2.0f / (e + 1.0f);
        }
        o.x = r[0]; o.y = r[1]; o.z = r[2]; o.w = r[3];
        *reinterpret_cast<float4*>(out + (size_t)(b0 + 2 * ty + i) * UNITS + u0 + 4 * tx) = o;
    }
}

extern "C" void kernel_launch(void* const* d_in, const int* in_sizes, int n_in,
                              void* d_out, int out_size, void* d_ws, size_t ws_size,
                              hipStream_t stream) {
    const float* x    = (const float*)d_in[0];
    const float* W    = (const float*)d_in[1];
    const float* bias = (const float*)d_in[2];
    float* out = (float*)d_out;

    dim3 grid(UNITS / BN, BATCH / BM);  // (8, 32) = 256 blocks
    dim3 block(512);
    maxexp_kernel<<<grid, block, 0, stream>>>(x, W, bias, out);
}